// Round 7
// baseline (234.102 us; speedup 1.0000x reference)
//
#include <hip/hip_runtime.h>
#include <cstdint>
#include <cstddef>
#include <cmath>

// Problem constants (from reference setup_inputs)
#define BB 64
#define TT 256
#define DD 512
#define BK 32
#define TILEM 64
#define NITER (TT / BK)
#define NTILE 36              // 8x8 lower-triangular 64x64 tiles per batch
#define SUBSZ 4096            // one sub-panel: [4 t-octets][64 cols] x 16B granules
#define BUFSZ 16384           // 4 sub-panels (A-rt, A-it, B-rt, B-it)

typedef short bf16x8 __attribute__((ext_vector_type(8)));  // 8 bf16 in 4 VGPRs
typedef float f32x4  __attribute__((ext_vector_type(4)));  // MFMA acc / 16B loads
typedef int   i32x4  __attribute__((ext_vector_type(4)));  // 16B LDS store

// fp32 -> bf16, round-half-up (1 add + shift; bias 2^-17, irrelevant vs threshold)
static __device__ __forceinline__ unsigned short f2bf(float x) {
  unsigned u = __builtin_bit_cast(unsigned, x) + 0x8000u;
  return (unsigned short)(u >> 16);
}

// ======================= Kernel 1: prep (scale+convert+transpose) ==========
// sqrt(w) trick: w>=0, so out_r = sum (sw*r)(sw*r)^T + (sw*i)(sw*i)^T and
// out_i = (sw*i)(sw*r)^T - (sw*r)(sw*i)^T with sw=sqrt(w): ONE pair of scaled
// arrays feeds both MFMA operands. Pre-pass writes rt,it as bf16 in
// TRANSPOSED [b][d][t] layout (t fastest) so the main kernel stages pure 16B
// granules (8 t-values per d-row) with no conversion work.
// Block = (b, t-tile 64, d-tile 64), both arrays. Grid 64*4*8 = 2048.
__global__ __launch_bounds__(256, 4)
void ComplexMixture_prep_kernel(const float* __restrict__ re,
                                const float* __restrict__ im,
                                const float* __restrict__ wt,
                                unsigned short* __restrict__ ws) {
  __shared__ float tile[64][65];   // +1 pad: conflict-free transpose
  const int L  = blockIdx.x;       // 0..2047
  const int b  = L >> 5;
  const int tt = (L >> 3) & 3;
  const int dt = L & 7;
  const int t0 = tt * 64, d0 = dt * 64;
  const int tid = threadIdx.x;
  const int rr = tid >> 4, rc = (tid & 15) * 4;  // read: 16 t-rows x 64 d f32
  const int dr = tid >> 2, tc = (tid & 3) * 16;  // write: 64 d-rows x 16 t bf16

  #pragma unroll
  for (int a = 0; a < 2; ++a) {
    const float* in = a ? im : re;
    unsigned short* ob = ws + (size_t)a * BB * DD * TT;
    if (a) __syncthreads();        // protect tile reuse across arrays
    #pragma unroll
    for (int p = 0; p < 4; ++p) {
      const int trow = p * 16 + rr;
      const float s = sqrtf(wt[b * TT + t0 + trow]);
      const f32x4 v = *(const f32x4*)(in + ((size_t)(b * TT + t0 + trow)) * DD + d0 + rc);
      tile[trow][rc + 0] = v[0] * s;
      tile[trow][rc + 1] = v[1] * s;
      tile[trow][rc + 2] = v[2] * s;
      tile[trow][rc + 3] = v[3] * s;
    }
    __syncthreads();
    union { unsigned short h[8]; i32x4 q; } u0, u1;
    #pragma unroll
    for (int j = 0; j < 8; ++j) {
      u0.h[j] = f2bf(tile[tc + j][dr]);
      u1.h[j] = f2bf(tile[tc + 8 + j][dr]);
    }
    unsigned short* o = ob + ((size_t)(b * DD + d0 + dr)) * TT + t0 + tc;
    *(i32x4*)o       = u0.q;
    *(i32x4*)(o + 8) = u1.q;
  }
}

// ======================= Kernel 2: main (reads bf16 workspace) =============
// Round-6 lesson: wall time ~= panel-read bytes / (~6.3-7.4 TB/s L2-L3 read
// plateau) across ALL structures; occupancy/pipeline/tile changes null.
// This version halves read bytes (bf16 ws) and strips staging to 4x 16B
// granule copies per lane per iter -> launch_bounds(256,4) (16 waves/CU).
// Keeps: tri-tile map + XCD swizzle, 1-deep prefetch with fused
// {s_waitcnt lgkmcnt(0); s_barrier} (vmcnt NOT drained across the barrier),
// XOR granule swizzle c(d) = (d&~3)|((d&3)^((d>>2)&3)^((d>>4)&1)) on both
// the ds_write slot and the frag-read address, slab epilogue (f32x4 stores).
__global__ __launch_bounds__(256, 4)
void ComplexMixture_54838142435828_kernel(const unsigned short* __restrict__ ws,
                                          float* __restrict__ out) {
  __shared__ __attribute__((aligned(16))) char smem[2 * BUFSZ];

  const int tid = threadIdx.x;

  // ---- XCD-cluster swizzle + triangular tile map ----
  const int L = blockIdx.x;        // 0..2303
  const int c = L & 7;             // XCD (round-robin dispatch by linear id)
  const int s = L >> 3;            // 0..287 within XCD
  const int b  = c * 8 + s / NTILE;
  const int t  = s % NTILE;
  int ti = (int)((sqrtf(8.f * (float)t + 1.f) - 1.f) * 0.5f);
  if ((ti + 1) * (ti + 2) / 2 <= t) ++ti;
  if (ti * (ti + 1) / 2 > t) --ti;
  const int tj = t - ti * (ti + 1) / 2;   // ti >= tj
  const int d0 = ti * TILEM;
  const int e0 = tj * TILEM;

  const int lane = tid & 63;
  const int wid  = tid >> 6;          // 0..3
  const int wm   = (wid >> 1) * 32;   // wave row offset (2x2 wave grid)
  const int wn   = (wid & 1) * 32;    // wave col offset
  const int quad = lane >> 4;
  const int l16  = lane & 15;

  // ---- staging roles: wave = sub-panel; wid 0:A-rt 1:A-it 2:B-rt 3:B-it ----
  const unsigned short* wsr = ws;
  const unsigned short* wsi = ws + (size_t)BB * DD * TT;
  const unsigned short* src = (wid & 1) ? wsi : wsr;
  const int panel  = (wid < 2) ? d0 : e0;  // diag: B reads same addrs -> L1 hits
  const int subOff = wid * SUBSZ;
  // lane covers d-col = lane; its 4 k-octet granules are 64 contiguous bytes
  const unsigned short* gsrc = src + ((size_t)(b * DD + panel + lane)) * TT;
  const int slotC = (lane & ~3) | ((lane & 3) ^ ((lane >> 2) & 3) ^ ((lane >> 4) & 1));

  f32x4 accR[2][2], accI[2][2];
  #pragma unroll
  for (int mt = 0; mt < 2; ++mt)
    #pragma unroll
    for (int nt = 0; nt < 2; ++nt) {
      accR[mt][nt] = (f32x4){0.f, 0.f, 0.f, 0.f};
      accI[mt][nt] = (f32x4){0.f, 0.f, 0.f, 0.f};
    }

  i32x4 v[4];

  // ---------------- prologue: load kt=0, stage into buffer 0 -----------------
  #pragma unroll
  for (int oc = 0; oc < 4; ++oc)
    v[oc] = *(const i32x4*)(gsrc + oc * 8);
  {
    char* wb = smem + subOff;
    #pragma unroll
    for (int oc = 0; oc < 4; ++oc)
      *(i32x4*)(wb + (oc * 64 + slotC) * 16) = v[oc];
  }

  // ---------------- pipelined k-loop (8 iters, fully unrolled) ---------------
  #pragma unroll
  for (int it = 0; it < NITER; ++it) {
    const int ktn = it * BK + BK;
    const int rbo = (it & 1) * BUFSZ;

    if (ktn < TT) {  // issue NEXT iter's global loads; they stay in flight
      #pragma unroll
      for (int oc = 0; oc < 4; ++oc)
        v[oc] = *(const i32x4*)(gsrc + ktn + oc * 8);
    }

    // Release our ds_writes + barrier, in ONE asm: vmcnt NOT drained (global
    // prefetch stays in flight); no memory op can cross in either direction.
    asm volatile("s_waitcnt lgkmcnt(0)\n\ts_barrier" ::: "memory");

    // fragment reads from buf[it&1] (read swizzle == write swizzle with d=r)
    const char* rb = smem + rbo;
    bf16x8 aR[2], aI[2], bR[2], bI[2];
    #pragma unroll
    for (int mt = 0; mt < 2; ++mt) {
      const int r  = wm + mt * 16 + l16;
      const int gi = (quad * 64 + (r & ~3) +
                      ((r & 3) ^ ((r >> 2) & 3) ^ ((r >> 4) & 1))) * 16;
      aR[mt] = *(const bf16x8*)(rb + gi);
      aI[mt] = *(const bf16x8*)(rb + SUBSZ + gi);
    }
    #pragma unroll
    for (int nt = 0; nt < 2; ++nt) {
      const int r  = wn + nt * 16 + l16;
      const int gi = (quad * 64 + (r & ~3) +
                      ((r & 3) ^ ((r >> 2) & 3) ^ ((r >> 4) & 1))) * 16;
      bR[nt] = *(const bf16x8*)(rb + 2 * SUBSZ + gi);
      bI[nt] = *(const bf16x8*)(rb + 3 * SUBSZ + gi);
    }

    #pragma unroll
    for (int mt = 0; mt < 2; ++mt) {
      const bf16x8 aRn = aR[mt] ^ (bf16x8)((short)0x8000);  // -rt via sign flip
      #pragma unroll
      for (int nt = 0; nt < 2; ++nt) {
        accR[mt][nt] = __builtin_amdgcn_mfma_f32_16x16x32_bf16(aR[mt], bR[nt], accR[mt][nt], 0, 0, 0);
        accR[mt][nt] = __builtin_amdgcn_mfma_f32_16x16x32_bf16(aI[mt], bI[nt], accR[mt][nt], 0, 0, 0);
        accI[mt][nt] = __builtin_amdgcn_mfma_f32_16x16x32_bf16(aI[mt], bR[nt], accI[mt][nt], 0, 0, 0);
        accI[mt][nt] = __builtin_amdgcn_mfma_f32_16x16x32_bf16(aRn,    bI[nt], accI[mt][nt], 0, 0, 0);
      }
    }

    if (ktn < TT) {  // stage next buffer (vmcnt auto-waited by compiler here)
      char* wb = smem + ((it & 1) ^ 1) * BUFSZ + subOff;
      #pragma unroll
      for (int oc = 0; oc < 4; ++oc)
        *(i32x4*)(wb + (oc * 64 + slotC) * 16) = v[oc];
    }
  }

  // ---------------- epilogue: slab-transposed f32x4 stores -------------------
  // Slab = buffer 0 (it=7 reads buffer 1; the it=7 fused lgkmcnt(0)+barrier
  // guarantees all waves' buffer-0 reads completed). Wave-private 4 KB:
  // [16 d-rows][32 e-cols] f32, col swizzled ^(quad-of-row<<3).
  const size_t NOFF = (size_t)BB * DD * DD;
  float* tbR = (float*)(smem + wid * SUBSZ);
  float* tbI = tbR + 512;
  const bool offdiag = (ti != tj);

  #pragma unroll
  for (int mt = 0; mt < 2; ++mt) {
    #pragma unroll
    for (int nt = 0; nt < 2; ++nt)
      #pragma unroll
      for (int r = 0; r < 4; ++r) {
        const int a = (quad * 4 + r) * 32 + ((nt * 16 + l16) ^ (quad << 3));
        tbR[a] = accR[mt][nt][r];
        tbI[a] = accI[mt][nt][r];
      }
    // direct tile: lane -> d-row lane>>2, e-chunk (lane&3)*8; full-line stores
    {
      const int rowD = lane >> 2;
      const int ech  = (lane & 3) * 8;
      const int a0   = rowD * 32 + (ech ^ ((rowD >> 2) << 3));
      const f32x4 r0 = *(const f32x4*)&tbR[a0];
      const f32x4 r1 = *(const f32x4*)&tbR[a0 + 4];
      const f32x4 i0 = *(const f32x4*)&tbI[a0];
      const f32x4 i1 = *(const f32x4*)&tbI[a0 + 4];
      const size_t ro = ((size_t)(b * DD + d0 + wm + mt * 16 + rowD)) * DD
                      + (size_t)(e0 + wn + ech);
      *(f32x4*)&out[ro]            = r0;
      *(f32x4*)&out[ro + 4]        = r1;
      *(f32x4*)&out[NOFF + ro]     = i0;
      *(f32x4*)&out[NOFF + ro + 4] = i1;
    }
    // mirrored tile (off-diag): out_r sym copy, out_i antisym negate
    if (offdiag) {
      const int er = lane & 31;
      const int hf = lane >> 5;
      f32x4 rr0, rr1, ii0, ii1;
      #pragma unroll
      for (int j2 = 0; j2 < 4; ++j2) {
        const int p0 = hf * 8 + j2;
        const int p1 = hf * 8 + 4 + j2;
        const int a0 = p0 * 32 + (er ^ ((p0 >> 2) << 3));
        const int a1 = p1 * 32 + (er ^ ((p1 >> 2) << 3));
        rr0[j2] =  tbR[a0];
        rr1[j2] =  tbR[a1];
        ii0[j2] = -tbI[a0];
        ii1[j2] = -tbI[a1];
      }
      const size_t mo = ((size_t)(b * DD + e0 + wn + er)) * DD
                      + (size_t)(d0 + wm + mt * 16 + hf * 8);
      *(f32x4*)&out[mo]            = rr0;
      *(f32x4*)&out[mo + 4]        = rr1;
      *(f32x4*)&out[NOFF + mo]     = ii0;
      *(f32x4*)&out[NOFF + mo + 4] = ii1;
    }
  }
}

// ======================= Fallback: proven round-6 kernel (fp32 direct) =====
// Used only if ws_size is too small for the 33.5 MB bf16 workspace.
__global__ __launch_bounds__(256, 3)
void ComplexMixture_fb_kernel(const float* __restrict__ re,
                              const float* __restrict__ im,
                              const float* __restrict__ wt,
                              float* __restrict__ out) {
  __shared__ __attribute__((aligned(16))) char smem[2 * BUFSZ];
  const int tid = threadIdx.x;
  const int L = blockIdx.x;
  const int c = L & 7;
  const int s = L >> 3;
  const int b  = c * 8 + s / NTILE;
  const int t  = s % NTILE;
  int ti = (int)((sqrtf(8.f * (float)t + 1.f) - 1.f) * 0.5f);
  if ((ti + 1) * (ti + 2) / 2 <= t) ++ti;
  if (ti * (ti + 1) / 2 > t) --ti;
  const int tj = t - ti * (ti + 1) / 2;
  const int d0 = ti * TILEM;
  const int e0 = tj * TILEM;
  const int lane = tid & 63;
  const int wid  = tid >> 6;
  const int wm   = (wid >> 1) * 32;
  const int wn   = (wid & 1) * 32;
  const int quad = lane >> 4;
  const int l16  = lane & 15;
  const bool aside = (wid < 2);
  const float* src = (wid & 1) ? im : re;
  const int panel  = aside ? d0 : e0;
  const int subOff = wid * SUBSZ;
  const int tq = lane & 15;
  const int th = lane >> 4;
  int wgo[4];
  #pragma unroll
  for (int dd = 0; dd < 4; ++dd)
    wgo[dd] = (th * 64 + 4 * tq + (dd ^ (tq & 3) ^ ((tq >> 2) & 1))) * 16;
  const size_t colBase = (size_t)(b * TT) * DD + panel + tq * 4;
  const float* wtb = wt + b * TT;
  f32x4 accR[2][2], accI[2][2];
  #pragma unroll
  for (int mt = 0; mt < 2; ++mt)
    #pragma unroll
    for (int nt = 0; nt < 2; ++nt) {
      accR[mt][nt] = (f32x4){0.f, 0.f, 0.f, 0.f};
      accI[mt][nt] = (f32x4){0.f, 0.f, 0.f, 0.f};
    }
  f32x4 v[8];
  f32x4 w0 = (f32x4){1.f,1.f,1.f,1.f}, w1 = w0;
  #pragma unroll
  for (int k = 0; k < 8; ++k)
    v[k] = *(const f32x4*)(src + colBase + (size_t)(th * 8 + k) * DD);
  if (aside) {
    w0 = *(const f32x4*)(wtb + th * 8);
    w1 = *(const f32x4*)(wtb + th * 8 + 4);
  }
  {
    char* wb = smem + subOff;
    if (aside) {
      #pragma unroll
      for (int k = 0; k < 4; ++k) v[k] *= w0[k];
      #pragma unroll
      for (int k = 0; k < 4; ++k) v[k + 4] *= w1[k];
    }
    #pragma unroll
    for (int dd = 0; dd < 4; ++dd) {
      union { unsigned short hh[8]; i32x4 q; } u;
      #pragma unroll
      for (int j = 0; j < 8; ++j) u.hh[j] = f2bf(v[j][dd]);
      *(i32x4*)(wb + wgo[dd]) = u.q;
    }
  }
  #pragma unroll
  for (int it = 0; it < NITER; ++it) {
    const int ktn = it * BK + BK;
    const int rbo = (it & 1) * BUFSZ;
    if (ktn < TT) {
      #pragma unroll
      for (int k = 0; k < 8; ++k)
        v[k] = *(const f32x4*)(src + colBase + (size_t)(ktn + th * 8 + k) * DD);
      if (aside) {
        w0 = *(const f32x4*)(wtb + ktn + th * 8);
        w1 = *(const f32x4*)(wtb + ktn + th * 8 + 4);
      }
    }
    asm volatile("s_waitcnt lgkmcnt(0)\n\ts_barrier" ::: "memory");
    const char* rb = smem + rbo;
    bf16x8 aR[2], aI[2], bR[2], bI[2];
    #pragma unroll
    for (int mt = 0; mt < 2; ++mt) {
      const int r  = wm + mt * 16 + l16;
      const int gi = (quad * 64 + (r & ~3) +
                      ((r & 3) ^ ((r >> 2) & 3) ^ ((r >> 4) & 1))) * 16;
      aR[mt] = *(const bf16x8*)(rb + gi);
      aI[mt] = *(const bf16x8*)(rb + SUBSZ + gi);
    }
    #pragma unroll
    for (int nt = 0; nt < 2; ++nt) {
      const int r  = wn + nt * 16 + l16;
      const int gi = (quad * 64 + (r & ~3) +
                      ((r & 3) ^ ((r >> 2) & 3) ^ ((r >> 4) & 1))) * 16;
      bR[nt] = *(const bf16x8*)(rb + 2 * SUBSZ + gi);
      bI[nt] = *(const bf16x8*)(rb + 3 * SUBSZ + gi);
    }
    #pragma unroll
    for (int mt = 0; mt < 2; ++mt) {
      const bf16x8 aRn = aR[mt] ^ (bf16x8)((short)0x8000);
      #pragma unroll
      for (int nt = 0; nt < 2; ++nt) {
        accR[mt][nt] = __builtin_amdgcn_mfma_f32_16x16x32_bf16(aR[mt], bR[nt], accR[mt][nt], 0, 0, 0);
        accR[mt][nt] = __builtin_amdgcn_mfma_f32_16x16x32_bf16(aI[mt], bI[nt], accR[mt][nt], 0, 0, 0);
        accI[mt][nt] = __builtin_amdgcn_mfma_f32_16x16x32_bf16(aI[mt], bR[nt], accI[mt][nt], 0, 0, 0);
        accI[mt][nt] = __builtin_amdgcn_mfma_f32_16x16x32_bf16(aRn,    bI[nt], accI[mt][nt], 0, 0, 0);
      }
    }
    if (ktn < TT) {
      char* wb = smem + ((it & 1) ^ 1) * BUFSZ + subOff;
      if (aside) {
        #pragma unroll
        for (int k = 0; k < 4; ++k) v[k] *= w0[k];
        #pragma unroll
        for (int k = 0; k < 4; ++k) v[k + 4] *= w1[k];
      }
      #pragma unroll
      for (int dd = 0; dd < 4; ++dd) {
        union { unsigned short hh[8]; i32x4 q; } u;
        #pragma unroll
        for (int j = 0; j < 8; ++j) u.hh[j] = f2bf(v[j][dd]);
        *(i32x4*)(wb + wgo[dd]) = u.q;
      }
    }
  }
  const size_t NOFF = (size_t)BB * DD * DD;
  float* tbR = (float*)(smem + wid * SUBSZ);
  float* tbI = tbR + 512;
  const bool offdiag = (ti != tj);
  #pragma unroll
  for (int mt = 0; mt < 2; ++mt) {
    #pragma unroll
    for (int nt = 0; nt < 2; ++nt)
      #pragma unroll
      for (int r = 0; r < 4; ++r) {
        const int a = (quad * 4 + r) * 32 + ((nt * 16 + l16) ^ (quad << 3));
        tbR[a] = accR[mt][nt][r];
        tbI[a] = accI[mt][nt][r];
      }
    {
      const int rowD = lane >> 2;
      const int ech  = (lane & 3) * 8;
      const int a0   = rowD * 32 + (ech ^ ((rowD >> 2) << 3));
      const f32x4 r0 = *(const f32x4*)&tbR[a0];
      const f32x4 r1 = *(const f32x4*)&tbR[a0 + 4];
      const f32x4 i0 = *(const f32x4*)&tbI[a0];
      const f32x4 i1 = *(const f32x4*)&tbI[a0 + 4];
      const size_t ro = ((size_t)(b * DD + d0 + wm + mt * 16 + rowD)) * DD
                      + (size_t)(e0 + wn + ech);
      *(f32x4*)&out[ro]            = r0;
      *(f32x4*)&out[ro + 4]        = r1;
      *(f32x4*)&out[NOFF + ro]     = i0;
      *(f32x4*)&out[NOFF + ro + 4] = i1;
    }
    if (offdiag) {
      const int er = lane & 31;
      const int hf = lane >> 5;
      f32x4 rr0, rr1, ii0, ii1;
      #pragma unroll
      for (int j2 = 0; j2 < 4; ++j2) {
        const int p0 = hf * 8 + j2;
        const int p1 = hf * 8 + 4 + j2;
        const int a0 = p0 * 32 + (er ^ ((p0 >> 2) << 3));
        const int a1 = p1 * 32 + (er ^ ((p1 >> 2) << 3));
        rr0[j2] =  tbR[a0];
        rr1[j2] =  tbR[a1];
        ii0[j2] = -tbI[a0];
        ii1[j2] = -tbI[a1];
      }
      const size_t mo = ((size_t)(b * DD + e0 + wn + er)) * DD
                      + (size_t)(d0 + wm + mt * 16 + hf * 8);
      *(f32x4*)&out[mo]            = rr0;
      *(f32x4*)&out[mo + 4]        = rr1;
      *(f32x4*)&out[NOFF + mo]     = ii0;
      *(f32x4*)&out[NOFF + mo + 4] = ii1;
    }
  }
}

extern "C" void kernel_launch(void* const* d_in, const int* in_sizes, int n_in,
                              void* d_out, int out_size, void* d_ws, size_t ws_size,
                              hipStream_t stream) {
  const float* re = (const float*)d_in[0];
  const float* im = (const float*)d_in[1];
  const float* wt = (const float*)d_in[2];
  float* out = (float*)d_out;
  const size_t need = (size_t)2 * BB * DD * TT * sizeof(unsigned short);  // 33.5 MB
  if (d_ws != nullptr && ws_size >= need) {
    unsigned short* ws = (unsigned short*)d_ws;
    ComplexMixture_prep_kernel<<<dim3(BB * 32), dim3(256), 0, stream>>>(re, im, wt, ws);
    ComplexMixture_54838142435828_kernel<<<dim3(BB * NTILE), dim3(256), 0, stream>>>(ws, out);
  } else {
    ComplexMixture_fb_kernel<<<dim3(BB * NTILE), dim3(256), 0, stream>>>(re, im, wt, out);
  }
}